// Round 5
// baseline (293.467 us; speedup 1.0000x reference)
//
#include <hip/hip_runtime.h>

#define N_NODES 100000
#define N_EDGES 1000000
#define EPS 1e-5f
#define SLOPE 0.01f
#define NBLK 391    // ceil(N_NODES/256)
#define GBLK4 1563  // ceil(N_NODES*4/256): 64 nodes/block, 4 threads/node

// ---------------------------------------------------------------------------
// ws layout:
//   P        : E * 32 B (32 MB)  {float4 ef; int src; pad} in CSR(dst) order
//   hist     : N ints   [zeroed] in-degree
//   cursor   : N ints   [zeroed] scatter cursor
//   stats    : 32 floats[zeroed] sum[16], sumsq[16]
//   row_part : N ints
//   bsum     : 512 ints
//   bsum_ex  : 512 ints
// Measured facts driving this design:
//   r1/r3: random scatter write costs a full 64 B line regardless of payload
//          size -> scatter the whole 32 B payload, gather becomes sequential.
//   r4:    fused gather at 1 thread/node = 15.6% occupancy (100k threads on a
//          524k-slot chip) -> latency-starved. Split feature dim across 4
//          threads/node; group-of-4 reduces via shfl_xor (no LDS barrier).
// ---------------------------------------------------------------------------

// Kernel 1: in-degree histogram (4 edges/thread, int4 loads).
__global__ __launch_bounds__(256) void count_kernel(
    const int* __restrict__ edge_index,
    int* __restrict__ hist)
{
    int i = blockIdx.x * 256 + threadIdx.x;
    if (i >= N_EDGES / 4) return;
    int4 d = *(const int4*)(edge_index + N_EDGES + i * 4);
    atomicAdd(hist + d.x, 1);
    atomicAdd(hist + d.y, 1);
    atomicAdd(hist + d.z, 1);
    atomicAdd(hist + d.w, 1);
}

// Kernel 2: block-local exclusive scan of hist + block sums.
__global__ __launch_bounds__(256) void scan1_kernel(
    const int* __restrict__ hist,
    int* __restrict__ row_part,
    int* __restrict__ bsum)
{
    __shared__ int s[256];
    int tid = threadIdx.x;
    int idx = blockIdx.x * 256 + tid;
    int val = (idx < N_NODES) ? hist[idx] : 0;
    s[tid] = val;
    __syncthreads();
    #pragma unroll
    for (int off = 1; off < 256; off <<= 1) {
        int t = (tid >= off) ? s[tid - off] : 0;
        __syncthreads();
        s[tid] += t;
        __syncthreads();
    }
    if (idx < N_NODES) row_part[idx] = s[tid] - val;
    if (tid == 255) bsum[blockIdx.x] = s[255];
}

// Kernel 3: exclusive scan of block sums (single block of 512).
__global__ __launch_bounds__(512) void scan2_kernel(
    const int* __restrict__ bsum,
    int* __restrict__ bsum_ex)
{
    __shared__ int s[512];
    int tid = threadIdx.x;
    int val = (tid < NBLK) ? bsum[tid] : 0;
    s[tid] = val;
    __syncthreads();
    #pragma unroll
    for (int off = 1; off < 512; off <<= 1) {
        int t = (tid >= off) ? s[tid - off] : 0;
        __syncthreads();
        s[tid] += t;
        __syncthreads();
    }
    bsum_ex[tid] = s[tid] - val;
}

// ---------------------------------------------------------------------------
// Kernel 4: scatter the FULL edge payload {ef, src} into CSR(dst) slot order.
// One aligned 32 B random write per edge (same line cost as a 4 B scatter,
// measured) buys a fully-sequential aggregation pass. Rank via atomic cursor.
// ---------------------------------------------------------------------------
__global__ __launch_bounds__(256) void scatter_kernel(
    const float* __restrict__ efeat,
    const int* __restrict__ edge_index,
    const int* __restrict__ row_part,
    const int* __restrict__ bsum_ex,
    int* __restrict__ cursor,
    float4* __restrict__ P)
{
    int eid = blockIdx.x * 256 + threadIdx.x;
    if (eid >= N_EDGES) return;
    int src = edge_index[eid];
    int dst = edge_index[N_EDGES + eid];
    float4 ef = *(const float4*)(efeat + (size_t)eid * 4);
    int slot = row_part[dst] + bsum_ex[dst >> 8] + atomicAdd(cursor + dst, 1);
    P[(size_t)2 * slot]     = ef;
    P[(size_t)2 * slot + 1] = make_float4(__int_as_float(src), 0.f, 0.f, 0.f);
}

// ---------------------------------------------------------------------------
// Kernel 5 (fused gather + node): 4 threads/node, thread t owns v-columns
// [4t, 4t+4). Group of 4 lanes reads v[src] as one coalesced 64 B line.
// Per-thread 20-reg accumulator; contraction + root computed as 16-wide
// partials, reduced across the group with shfl_xor(1),shfl_xor(2) — no LDS,
// no barrier in the hot path. 400k threads -> full latency hiding.
// ---------------------------------------------------------------------------
__global__ __launch_bounds__(256) void gather_node_kernel(
    const float* __restrict__ v,
    const float4* __restrict__ P,
    const int* __restrict__ hist,
    const int* __restrict__ row_part,
    const int* __restrict__ bsum_ex,
    const float* __restrict__ enet_w,
    const float* __restrict__ enet_b,
    const float* __restrict__ root,
    const float* __restrict__ bias,
    float* __restrict__ out,
    float* __restrict__ stats)
{
    int tid = blockIdx.x * 256 + threadIdx.x;
    int n = tid >> 2;          // node
    int t = tid & 3;           // feature-quarter owner
    bool active = (n < N_NODES);

    // acc[c*4+q]: component c in {1, ef.x, ef.y, ef.z, ef.w}, my quarter q
    float acc[20];
    #pragma unroll
    for (int i = 0; i < 20; ++i) acc[i] = 0.0f;

    int deg = 0, start = 0;
    if (active) {
        start = row_part[n] + bsum_ex[n >> 8];
        deg = hist[n];
    }

    const float4* pp = P + (size_t)2 * start;
    for (int j = 0; j < deg; ++j) {
        float4 ef = pp[2 * j];                       // same line across group
        float4 sp = pp[2 * j + 1];
        int src = __float_as_int(sp.x);
        float4 a = *(const float4*)(v + (size_t)src * 16 + t * 4); // coalesced
        acc[ 0] += a.x;              acc[ 1] += a.y;
        acc[ 2] += a.z;              acc[ 3] += a.w;
        acc[ 4] = fmaf(ef.x, a.x, acc[ 4]);
        acc[ 5] = fmaf(ef.x, a.y, acc[ 5]);
        acc[ 6] = fmaf(ef.x, a.z, acc[ 6]);
        acc[ 7] = fmaf(ef.x, a.w, acc[ 7]);
        acc[ 8] = fmaf(ef.y, a.x, acc[ 8]);
        acc[ 9] = fmaf(ef.y, a.y, acc[ 9]);
        acc[10] = fmaf(ef.y, a.z, acc[10]);
        acc[11] = fmaf(ef.y, a.w, acc[11]);
        acc[12] = fmaf(ef.z, a.x, acc[12]);
        acc[13] = fmaf(ef.z, a.y, acc[13]);
        acc[14] = fmaf(ef.z, a.z, acc[14]);
        acc[15] = fmaf(ef.z, a.w, acc[15]);
        acc[16] = fmaf(ef.w, a.x, acc[16]);
        acc[17] = fmaf(ef.w, a.y, acc[17]);
        acc[18] = fmaf(ef.w, a.z, acc[18]);
        acc[19] = fmaf(ef.w, a.w, acc[19]);
    }

    // per-thread 16-wide partial: message (scaled) + root term over my i-range
    float partial[16];
    if (active) {
        float scale = 1.0f / fmaxf((float)deg, 1.0f);
        float4 vq = *(const float4*)(v + (size_t)n * 16 + t * 4);
        float vn_[4] = {vq.x, vq.y, vq.z, vq.w};
        #pragma unroll
        for (int o = 0; o < 16; ++o) {
            float m = 0.0f;
            #pragma unroll
            for (int il = 0; il < 4; ++il) {
                int i = t * 4 + il;
                m = fmaf(acc[il], enet_b[i * 16 + o], m);            // S0 * B
                #pragma unroll
                for (int k = 0; k < 4; ++k)
                    m = fmaf(acc[(k + 1) * 4 + il],
                             enet_w[(i * 16 + o) * 4 + k], m);       // Sk * Wk
            }
            float r = 0.0f;
            #pragma unroll
            for (int il = 0; il < 4; ++il)
                r = fmaf(vn_[il], root[(t * 4 + il) * 16 + o], r);
            partial[o] = fmaf(m, scale, r);
        }
    } else {
        #pragma unroll
        for (int o = 0; o < 16; ++o) partial[o] = 0.0f;
    }

    // group-of-4 reduction (lanes 4g..4g+3 share node n)
    float val[16];
    #pragma unroll
    for (int o = 0; o < 16; ++o) {
        float a = partial[o];
        a += __shfl_xor(a, 1, 64);
        a += __shfl_xor(a, 2, 64);
        val[o] = active ? (a + bias[o]) : 0.0f;
    }

    if (active) {
        // each lane writes its quarter (val replicated in group) — coalesced
        *(float4*)(out + (size_t)n * 16 + t * 4) =
            make_float4(val[t*4+0], val[t*4+1], val[t*4+2], val[t*4+3]);
    }

    // batch stats: every node counted 4x (val replicated) -> scale by 0.25
    float ssum[16], ssq[16];
    #pragma unroll
    for (int o = 0; o < 16; ++o) {
        float a = val[o];
        float b = a * a;
        #pragma unroll
        for (int m = 1; m < 64; m <<= 1) {
            a += __shfl_xor(a, m, 64);
            b += __shfl_xor(b, m, 64);
        }
        ssum[o] = a; ssq[o] = b;
    }
    __shared__ float part[4][32];
    int wave = threadIdx.x >> 6;
    int lane = threadIdx.x & 63;
    if (lane == 0) {
        #pragma unroll
        for (int o = 0; o < 16; ++o) {
            part[wave][o]      = ssum[o] * 0.25f;
            part[wave][16 + o] = ssq[o] * 0.25f;
        }
    }
    __syncthreads();
    if (threadIdx.x < 32) {
        float s = part[0][threadIdx.x] + part[1][threadIdx.x] +
                  part[2][threadIdx.x] + part[3][threadIdx.x];
        unsafeAtomicAdd(stats + threadIdx.x, s);
    }
}

// Kernel 6: BatchNorm (batch stats) + LeakyReLU, in place, float4-vectorized.
__global__ __launch_bounds__(256) void final_kernel(
    float* __restrict__ out,
    const float* __restrict__ stats,
    const float* __restrict__ gamma,
    const float* __restrict__ beta)
{
    int idx = blockIdx.x * 256 + threadIdx.x;      // float4 index
    if (idx >= N_NODES * 4) return;
    int o0 = (idx & 3) << 2;
    const float invN = 1.0f / (float)N_NODES;
    float4 x = *((const float4*)out + idx);
    float xs[4] = {x.x, x.y, x.z, x.w};
    float r[4];
    #pragma unroll
    for (int u = 0; u < 4; ++u) {
        int o = o0 + u;
        float mu = stats[o] * invN;
        float var = fmaxf(stats[16 + o] * invN - mu * mu, 0.0f);
        float y = fmaf(gamma[o] * (xs[u] - mu), rsqrtf(var + EPS), beta[o]);
        r[u] = (y >= 0.0f) ? y : SLOPE * y;
    }
    *((float4*)out + idx) = make_float4(r[0], r[1], r[2], r[3]);
}

extern "C" void kernel_launch(void* const* d_in, const int* in_sizes, int n_in,
                              void* d_out, int out_size, void* d_ws, size_t ws_size,
                              hipStream_t stream)
{
    const float* v = (const float*)d_in[0];
    const float* e = (const float*)d_in[1];
    const int* edge_index = (const int*)d_in[2];
    const float* enet_w = (const float*)d_in[3];
    const float* enet_b = (const float*)d_in[4];
    const float* root = (const float*)d_in[5];
    const float* bias = (const float*)d_in[6];
    const float* gamma = (const float*)d_in[7];
    const float* beta = (const float*)d_in[8];
    float* out = (float*)d_out;

    char* ws = (char*)d_ws;
    float4* P        = (float4*)ws;                 ws += (size_t)N_EDGES * 32;
    int*    hist     = (int*)ws;                    ws += (size_t)N_NODES * 4;
    int*    cursor   = (int*)ws;                    ws += (size_t)N_NODES * 4;
    float*  stats    = (float*)ws;                  ws += 32 * 4;
    int*    row_part = (int*)ws;                    ws += (size_t)N_NODES * 4;
    int*    bsum     = (int*)ws;                    ws += 512 * 4;
    int*    bsum_ex  = (int*)ws;

    // zero hist + cursor + stats (contiguous)
    hipMemsetAsync(hist, 0, (size_t)N_NODES * 4 * 2 + 32 * 4, stream);

    count_kernel<<<(N_EDGES / 4 + 255) / 256, 256, 0, stream>>>(edge_index, hist);
    scan1_kernel<<<NBLK, 256, 0, stream>>>(hist, row_part, bsum);
    scan2_kernel<<<1, 512, 0, stream>>>(bsum, bsum_ex);
    scatter_kernel<<<(N_EDGES + 255) / 256, 256, 0, stream>>>(
        e, edge_index, row_part, bsum_ex, cursor, P);
    gather_node_kernel<<<GBLK4, 256, 0, stream>>>(
        v, P, hist, row_part, bsum_ex, enet_w, enet_b, root, bias, out, stats);
    final_kernel<<<(N_NODES * 4 + 255) / 256, 256, 0, stream>>>(
        out, stats, gamma, beta);
}

// Round 6
// 269.108 us; speedup vs baseline: 1.0905x; 1.0905x over previous
//
#include <hip/hip_runtime.h>

#define N_NODES 100000
#define N_EDGES 1000000
#define EPS 1e-5f
#define SLOPE 0.01f
#define NBLK 391    // ceil(N_NODES/256)
#define GBLK4 1563  // ceil(N_NODES*4/256): 64 nodes/block, 4 threads/node

// ---------------------------------------------------------------------------
// ws layout:
//   P        : E * 32 B (32 MB)  {float4 ef; int src; pad} in CSR(dst) order
//   hist     : N ints   [zeroed] in-degree
//   cursor   : N ints   [zeroed] scatter cursor
//   stats    : 32 floats[zeroed] sum[16], sumsq[16]
//   row_part : N ints
//   bsum     : 512 ints
//   bsum_ex  : 512 ints
// Measured design rules:
//   r1/r3: random scatter write costs one 64 B line regardless of payload
//          -> scatter whole 32 B payload once; aggregation reads sequential.
//   r4:    1 thr/node fused = grid-limited (391 blocks, 15.6% occ).
//   r5:    feature-split 4 thr/node = lanes BROADCAST same lines -> wave-level
//          MLP collapsed. Rule: extra threads must issue DISTINCT lines.
//   r6:    edge-split 4 thr/node: lane t does edges j%4==t, full acc[80];
//          group-reduce via shfl; 64 distinct v-lines/wave + coalesced P.
// ---------------------------------------------------------------------------

// Kernel 1: in-degree histogram (4 edges/thread, int4 loads).
__global__ __launch_bounds__(256) void count_kernel(
    const int* __restrict__ edge_index,
    int* __restrict__ hist)
{
    int i = blockIdx.x * 256 + threadIdx.x;
    if (i >= N_EDGES / 4) return;
    int4 d = *(const int4*)(edge_index + N_EDGES + i * 4);
    atomicAdd(hist + d.x, 1);
    atomicAdd(hist + d.y, 1);
    atomicAdd(hist + d.z, 1);
    atomicAdd(hist + d.w, 1);
}

// Kernel 2: block-local exclusive scan of hist + block sums.
__global__ __launch_bounds__(256) void scan1_kernel(
    const int* __restrict__ hist,
    int* __restrict__ row_part,
    int* __restrict__ bsum)
{
    __shared__ int s[256];
    int tid = threadIdx.x;
    int idx = blockIdx.x * 256 + tid;
    int val = (idx < N_NODES) ? hist[idx] : 0;
    s[tid] = val;
    __syncthreads();
    #pragma unroll
    for (int off = 1; off < 256; off <<= 1) {
        int t = (tid >= off) ? s[tid - off] : 0;
        __syncthreads();
        s[tid] += t;
        __syncthreads();
    }
    if (idx < N_NODES) row_part[idx] = s[tid] - val;
    if (tid == 255) bsum[blockIdx.x] = s[255];
}

// Kernel 3: exclusive scan of block sums (single block of 512).
__global__ __launch_bounds__(512) void scan2_kernel(
    const int* __restrict__ bsum,
    int* __restrict__ bsum_ex)
{
    __shared__ int s[512];
    int tid = threadIdx.x;
    int val = (tid < NBLK) ? bsum[tid] : 0;
    s[tid] = val;
    __syncthreads();
    #pragma unroll
    for (int off = 1; off < 512; off <<= 1) {
        int t = (tid >= off) ? s[tid - off] : 0;
        __syncthreads();
        s[tid] += t;
        __syncthreads();
    }
    bsum_ex[tid] = s[tid] - val;
}

// ---------------------------------------------------------------------------
// Kernel 4: scatter FULL edge payload {ef, src} into CSR(dst) slot order.
// ---------------------------------------------------------------------------
__global__ __launch_bounds__(256) void scatter_kernel(
    const float* __restrict__ efeat,
    const int* __restrict__ edge_index,
    const int* __restrict__ row_part,
    const int* __restrict__ bsum_ex,
    int* __restrict__ cursor,
    float4* __restrict__ P)
{
    int eid = blockIdx.x * 256 + threadIdx.x;
    if (eid >= N_EDGES) return;
    int src = edge_index[eid];
    int dst = edge_index[N_EDGES + eid];
    float4 ef = *(const float4*)(efeat + (size_t)eid * 4);
    int slot = row_part[dst] + bsum_ex[dst >> 8] + atomicAdd(cursor + dst, 1);
    P[(size_t)2 * slot]     = ef;
    P[(size_t)2 * slot + 1] = make_float4(__int_as_float(src), 0.f, 0.f, 0.f);
}

// ---------------------------------------------------------------------------
// Kernel 5 (fused gather + node): 4 threads/node, EDGE-split. Lane t of a
// group processes edges j = t, t+4, ... with full acc[80]; every lane issues
// its own random v-line (distinct-line MLP) and the group's P reads are 4
// consecutive 32 B records (coalesced). Group shfl-reduce of acc, then lane t
// computes output columns [4t,4t+4): contraction + root + bias, coalesced
// float4 out write. Stats via t-class butterfly. No LDS in the hot path.
// ---------------------------------------------------------------------------
__global__ __launch_bounds__(256) void gather_node_kernel(
    const float* __restrict__ v,
    const float4* __restrict__ P,
    const int* __restrict__ hist,
    const int* __restrict__ row_part,
    const int* __restrict__ bsum_ex,
    const float* __restrict__ enet_w,
    const float* __restrict__ enet_b,
    const float* __restrict__ root,
    const float* __restrict__ bias,
    float* __restrict__ out,
    float* __restrict__ stats)
{
    int tid = blockIdx.x * 256 + threadIdx.x;
    int n = tid >> 2;          // node
    int t = tid & 3;           // edge-stride class / output quarter
    bool active = (n < N_NODES);

    float acc[80];
    #pragma unroll
    for (int i = 0; i < 80; ++i) acc[i] = 0.0f;

    int deg = 0, start = 0;
    if (active) {
        start = row_part[n] + bsum_ex[n >> 8];
        deg = hist[n];
    }

    const float4* pp = P + (size_t)2 * start;
    for (int j = t; j < deg; j += 4) {
        float4 ef = pp[2 * j];
        float4 sp = pp[2 * j + 1];
        int src = __float_as_int(sp.x);
        const float4* vr = (const float4*)(v + (size_t)src * 16);
        #pragma unroll
        for (int i = 0; i < 4; ++i) {
            float4 a = vr[i];
            acc[     i*4+0] += a.x;
            acc[     i*4+1] += a.y;
            acc[     i*4+2] += a.z;
            acc[     i*4+3] += a.w;
            acc[16 + i*4+0] = fmaf(ef.x, a.x, acc[16 + i*4+0]);
            acc[16 + i*4+1] = fmaf(ef.x, a.y, acc[16 + i*4+1]);
            acc[16 + i*4+2] = fmaf(ef.x, a.z, acc[16 + i*4+2]);
            acc[16 + i*4+3] = fmaf(ef.x, a.w, acc[16 + i*4+3]);
            acc[32 + i*4+0] = fmaf(ef.y, a.x, acc[32 + i*4+0]);
            acc[32 + i*4+1] = fmaf(ef.y, a.y, acc[32 + i*4+1]);
            acc[32 + i*4+2] = fmaf(ef.y, a.z, acc[32 + i*4+2]);
            acc[32 + i*4+3] = fmaf(ef.y, a.w, acc[32 + i*4+3]);
            acc[48 + i*4+0] = fmaf(ef.z, a.x, acc[48 + i*4+0]);
            acc[48 + i*4+1] = fmaf(ef.z, a.y, acc[48 + i*4+1]);
            acc[48 + i*4+2] = fmaf(ef.z, a.z, acc[48 + i*4+2]);
            acc[48 + i*4+3] = fmaf(ef.z, a.w, acc[48 + i*4+3]);
            acc[64 + i*4+0] = fmaf(ef.w, a.x, acc[64 + i*4+0]);
            acc[64 + i*4+1] = fmaf(ef.w, a.y, acc[64 + i*4+1]);
            acc[64 + i*4+2] = fmaf(ef.w, a.z, acc[64 + i*4+2]);
            acc[64 + i*4+3] = fmaf(ef.w, a.w, acc[64 + i*4+3]);
        }
    }

    // group-of-4 reduction: all lanes end with the node's summed acc[80]
    #pragma unroll
    for (int i = 0; i < 80; ++i) {
        acc[i] += __shfl_xor(acc[i], 1, 64);
        acc[i] += __shfl_xor(acc[i], 2, 64);
    }

    // lane t computes output columns o = 4t..4t+3
    float val[4];
    if (active) {
        float scale = 1.0f / fmaxf((float)deg, 1.0f);
        float vn[16];
        #pragma unroll
        for (int i = 0; i < 4; ++i) {
            float4 tv = *(const float4*)(v + (size_t)n * 16 + i * 4);
            vn[4*i+0] = tv.x; vn[4*i+1] = tv.y;
            vn[4*i+2] = tv.z; vn[4*i+3] = tv.w;
        }
        #pragma unroll
        for (int u = 0; u < 4; ++u) {
            int o = 4 * t + u;
            float m = 0.0f;
            #pragma unroll
            for (int i = 0; i < 16; ++i) {
                m = fmaf(acc[i], enet_b[i * 16 + o], m);           // S0 * B
                #pragma unroll
                for (int k = 0; k < 4; ++k)
                    m = fmaf(acc[16 + k * 16 + i],
                             enet_w[(i * 16 + o) * 4 + k], m);     // Sk * Wk
            }
            float r = 0.0f;
            #pragma unroll
            for (int i = 0; i < 16; ++i)
                r = fmaf(vn[i], root[i * 16 + o], r);
            val[u] = fmaf(m, scale, r) + bias[o];
        }
        // group writes 4 consecutive quarters -> 64 B contiguous per node
        *(float4*)(out + (size_t)n * 16 + 4 * t) =
            make_float4(val[0], val[1], val[2], val[3]);
    } else {
        #pragma unroll
        for (int u = 0; u < 4; ++u) val[u] = 0.0f;
    }

    // stats: each (node, o) lives in exactly one lane. Butterfly over the
    // t-class (masks 4,8,16,32) sums the wave's 16 nodes; lanes 0..3 then
    // hold wave totals for o = lane*4+u.
    float s1[4], s2[4];
    #pragma unroll
    for (int u = 0; u < 4; ++u) {
        float a = val[u];
        float b = a * a;
        #pragma unroll
        for (int m = 4; m < 64; m <<= 1) {
            a += __shfl_xor(a, m, 64);
            b += __shfl_xor(b, m, 64);
        }
        s1[u] = a; s2[u] = b;
    }
    __shared__ float part[4][32];
    int wave = threadIdx.x >> 6;
    int lane = threadIdx.x & 63;
    if (lane < 4) {
        #pragma unroll
        for (int u = 0; u < 4; ++u) {
            part[wave][lane * 4 + u]      = s1[u];
            part[wave][16 + lane * 4 + u] = s2[u];
        }
    }
    __syncthreads();
    if (threadIdx.x < 32) {
        float s = part[0][threadIdx.x] + part[1][threadIdx.x] +
                  part[2][threadIdx.x] + part[3][threadIdx.x];
        unsafeAtomicAdd(stats + threadIdx.x, s);
    }
}

// Kernel 6: BatchNorm (batch stats) + LeakyReLU, in place, float4-vectorized.
__global__ __launch_bounds__(256) void final_kernel(
    float* __restrict__ out,
    const float* __restrict__ stats,
    const float* __restrict__ gamma,
    const float* __restrict__ beta)
{
    int idx = blockIdx.x * 256 + threadIdx.x;      // float4 index
    if (idx >= N_NODES * 4) return;
    int o0 = (idx & 3) << 2;
    const float invN = 1.0f / (float)N_NODES;
    float4 x = *((const float4*)out + idx);
    float xs[4] = {x.x, x.y, x.z, x.w};
    float r[4];
    #pragma unroll
    for (int u = 0; u < 4; ++u) {
        int o = o0 + u;
        float mu = stats[o] * invN;
        float var = fmaxf(stats[16 + o] * invN - mu * mu, 0.0f);
        float y = fmaf(gamma[o] * (xs[u] - mu), rsqrtf(var + EPS), beta[o]);
        r[u] = (y >= 0.0f) ? y : SLOPE * y;
    }
    *((float4*)out + idx) = make_float4(r[0], r[1], r[2], r[3]);
}

extern "C" void kernel_launch(void* const* d_in, const int* in_sizes, int n_in,
                              void* d_out, int out_size, void* d_ws, size_t ws_size,
                              hipStream_t stream)
{
    const float* v = (const float*)d_in[0];
    const float* e = (const float*)d_in[1];
    const int* edge_index = (const int*)d_in[2];
    const float* enet_w = (const float*)d_in[3];
    const float* enet_b = (const float*)d_in[4];
    const float* root = (const float*)d_in[5];
    const float* bias = (const float*)d_in[6];
    const float* gamma = (const float*)d_in[7];
    const float* beta = (const float*)d_in[8];
    float* out = (float*)d_out;

    char* ws = (char*)d_ws;
    float4* P        = (float4*)ws;                 ws += (size_t)N_EDGES * 32;
    int*    hist     = (int*)ws;                    ws += (size_t)N_NODES * 4;
    int*    cursor   = (int*)ws;                    ws += (size_t)N_NODES * 4;
    float*  stats    = (float*)ws;                  ws += 32 * 4;
    int*    row_part = (int*)ws;                    ws += (size_t)N_NODES * 4;
    int*    bsum     = (int*)ws;                    ws += 512 * 4;
    int*    bsum_ex  = (int*)ws;

    // zero hist + cursor + stats (contiguous)
    hipMemsetAsync(hist, 0, (size_t)N_NODES * 4 * 2 + 32 * 4, stream);

    count_kernel<<<(N_EDGES / 4 + 255) / 256, 256, 0, stream>>>(edge_index, hist);
    scan1_kernel<<<NBLK, 256, 0, stream>>>(hist, row_part, bsum);
    scan2_kernel<<<1, 512, 0, stream>>>(bsum, bsum_ex);
    scatter_kernel<<<(N_EDGES + 255) / 256, 256, 0, stream>>>(
        e, edge_index, row_part, bsum_ex, cursor, P);
    gather_node_kernel<<<GBLK4, 256, 0, stream>>>(
        v, P, hist, row_part, bsum_ex, enet_w, enet_b, root, bias, out, stats);
    final_kernel<<<(N_NODES * 4 + 255) / 256, 256, 0, stream>>>(
        out, stats, gamma, beta);
}

// Round 7
// 231.034 us; speedup vs baseline: 1.2702x; 1.1648x over previous
//
#include <hip/hip_runtime.h>

#define N_NODES 100000
#define N_EDGES 1000000
#define EPS 1e-5f
#define SLOPE 0.01f
#define NBLK 391    // ceil(N_NODES/256)

// ---------------------------------------------------------------------------
// ws layout:
//   P        : E * 32 B (32 MB)  {float4 ef; int src; pad} in CSR(dst) order
//   hist     : N ints   [zeroed] in-degree
//   cursor   : N ints   [zeroed] scatter cursor
//   stats    : 32 floats[zeroed] sum[16], sumsq[16]
//   row_part : N ints
//   bsum     : 512 ints
//   bsum_ex  : 512 ints
// Measured design rules:
//   r1/r3: random scatter write costs one 64 B line regardless of payload
//          -> scatter whole 32 B payload once; aggregation reads sequential.
//   r4:    1 thr/node fused gather = best shape; 0.9 TB/s at 15.6% occ =
//          request-concurrency-starved (r0 gather did 3.0 TB/s same pattern).
//   r5/r6: splitting a node across lanes loses (broadcast lines / VGPR-
//          replicated acc). Keep node-sequential; add ILP instead (r7).
// ---------------------------------------------------------------------------

// Kernel 1: in-degree histogram (4 edges/thread, int4 loads).
__global__ __launch_bounds__(256) void count_kernel(
    const int* __restrict__ edge_index,
    int* __restrict__ hist)
{
    int i = blockIdx.x * 256 + threadIdx.x;
    if (i >= N_EDGES / 4) return;
    int4 d = *(const int4*)(edge_index + N_EDGES + i * 4);
    atomicAdd(hist + d.x, 1);
    atomicAdd(hist + d.y, 1);
    atomicAdd(hist + d.z, 1);
    atomicAdd(hist + d.w, 1);
}

// Kernel 2: block-local exclusive scan of hist + block sums.
__global__ __launch_bounds__(256) void scan1_kernel(
    const int* __restrict__ hist,
    int* __restrict__ row_part,
    int* __restrict__ bsum)
{
    __shared__ int s[256];
    int tid = threadIdx.x;
    int idx = blockIdx.x * 256 + tid;
    int val = (idx < N_NODES) ? hist[idx] : 0;
    s[tid] = val;
    __syncthreads();
    #pragma unroll
    for (int off = 1; off < 256; off <<= 1) {
        int t = (tid >= off) ? s[tid - off] : 0;
        __syncthreads();
        s[tid] += t;
        __syncthreads();
    }
    if (idx < N_NODES) row_part[idx] = s[tid] - val;
    if (tid == 255) bsum[blockIdx.x] = s[255];
}

// Kernel 3: exclusive scan of block sums (single block of 512).
__global__ __launch_bounds__(512) void scan2_kernel(
    const int* __restrict__ bsum,
    int* __restrict__ bsum_ex)
{
    __shared__ int s[512];
    int tid = threadIdx.x;
    int val = (tid < NBLK) ? bsum[tid] : 0;
    s[tid] = val;
    __syncthreads();
    #pragma unroll
    for (int off = 1; off < 512; off <<= 1) {
        int t = (tid >= off) ? s[tid - off] : 0;
        __syncthreads();
        s[tid] += t;
        __syncthreads();
    }
    bsum_ex[tid] = s[tid] - val;
}

// ---------------------------------------------------------------------------
// Kernel 4: scatter FULL edge payload {ef, src} into CSR(dst) slot order.
// ---------------------------------------------------------------------------
__global__ __launch_bounds__(256) void scatter_kernel(
    const float* __restrict__ efeat,
    const int* __restrict__ edge_index,
    const int* __restrict__ row_part,
    const int* __restrict__ bsum_ex,
    int* __restrict__ cursor,
    float4* __restrict__ P)
{
    int eid = blockIdx.x * 256 + threadIdx.x;
    if (eid >= N_EDGES) return;
    int src = edge_index[eid];
    int dst = edge_index[N_EDGES + eid];
    float4 ef = *(const float4*)(efeat + (size_t)eid * 4);
    int slot = row_part[dst] + bsum_ex[dst >> 8] + atomicAdd(cursor + dst, 1);
    P[(size_t)2 * slot]     = ef;
    P[(size_t)2 * slot + 1] = make_float4(__int_as_float(src), 0.f, 0.f, 0.f);
}

// ---------------------------------------------------------------------------
// Kernel 5 (fused gather + node): 1 thread/node (r4 shape), hot loop
// UNROLLED x4: 4 P record-pairs loaded up front (256 B sequential), 4
// independent v-lines in flight, FMA blocks interleaved. Grid-limited
// occupancy means the extra VGPRs are free; the win is ~4x outstanding
// loads per thread (r4 was concurrency-starved at 0.9 TB/s).
// ---------------------------------------------------------------------------
__global__ __launch_bounds__(256) void gather_node_kernel(
    const float* __restrict__ v,
    const float4* __restrict__ P,
    const int* __restrict__ hist,
    const int* __restrict__ row_part,
    const int* __restrict__ bsum_ex,
    const float* __restrict__ enet_w,
    const float* __restrict__ enet_b,
    const float* __restrict__ root,
    const float* __restrict__ bias,
    float* __restrict__ out,
    float* __restrict__ stats)
{
    int n = blockIdx.x * 256 + threadIdx.x;
    bool active = (n < N_NODES);

    float acc[80];
    #pragma unroll
    for (int i = 0; i < 80; ++i) acc[i] = 0.0f;

    int deg = 0, start = 0;
    if (active) {
        start = row_part[n] + bsum_ex[n >> 8];
        deg = hist[n];
    }

    const float4* pp = P + (size_t)2 * start;
    int j = 0;
    for (; j + 4 <= deg; j += 4) {
        // 8 sequential float4 loads (4 records, 256 B) — issued together
        float4 ef0 = pp[2*j+0], sp0 = pp[2*j+1];
        float4 ef1 = pp[2*j+2], sp1 = pp[2*j+3];
        float4 ef2 = pp[2*j+4], sp2 = pp[2*j+5];
        float4 ef3 = pp[2*j+6], sp3 = pp[2*j+7];
        int s0 = __float_as_int(sp0.x);
        int s1 = __float_as_int(sp1.x);
        int s2 = __float_as_int(sp2.x);
        int s3 = __float_as_int(sp3.x);
        const float4* vr0 = (const float4*)(v + (size_t)s0 * 16);
        const float4* vr1 = (const float4*)(v + (size_t)s1 * 16);
        const float4* vr2 = (const float4*)(v + (size_t)s2 * 16);
        const float4* vr3 = (const float4*)(v + (size_t)s3 * 16);
        #pragma unroll
        for (int i = 0; i < 4; ++i) {
            // 4 independent random v-line loads in flight per i-step
            float4 a = vr0[i], b = vr1[i], c = vr2[i], d = vr3[i];
            acc[     i*4+0] += (a.x + b.x) + (c.x + d.x);
            acc[     i*4+1] += (a.y + b.y) + (c.y + d.y);
            acc[     i*4+2] += (a.z + b.z) + (c.z + d.z);
            acc[     i*4+3] += (a.w + b.w) + (c.w + d.w);
            acc[16 + i*4+0] = fmaf(ef0.x, a.x, fmaf(ef1.x, b.x,
                              fmaf(ef2.x, c.x, fmaf(ef3.x, d.x, acc[16 + i*4+0]))));
            acc[16 + i*4+1] = fmaf(ef0.x, a.y, fmaf(ef1.x, b.y,
                              fmaf(ef2.x, c.y, fmaf(ef3.x, d.y, acc[16 + i*4+1]))));
            acc[16 + i*4+2] = fmaf(ef0.x, a.z, fmaf(ef1.x, b.z,
                              fmaf(ef2.x, c.z, fmaf(ef3.x, d.z, acc[16 + i*4+2]))));
            acc[16 + i*4+3] = fmaf(ef0.x, a.w, fmaf(ef1.x, b.w,
                              fmaf(ef2.x, c.w, fmaf(ef3.x, d.w, acc[16 + i*4+3]))));
            acc[32 + i*4+0] = fmaf(ef0.y, a.x, fmaf(ef1.y, b.x,
                              fmaf(ef2.y, c.x, fmaf(ef3.y, d.x, acc[32 + i*4+0]))));
            acc[32 + i*4+1] = fmaf(ef0.y, a.y, fmaf(ef1.y, b.y,
                              fmaf(ef2.y, c.y, fmaf(ef3.y, d.y, acc[32 + i*4+1]))));
            acc[32 + i*4+2] = fmaf(ef0.y, a.z, fmaf(ef1.y, b.z,
                              fmaf(ef2.y, c.z, fmaf(ef3.y, d.z, acc[32 + i*4+2]))));
            acc[32 + i*4+3] = fmaf(ef0.y, a.w, fmaf(ef1.y, b.w,
                              fmaf(ef2.y, c.w, fmaf(ef3.y, d.w, acc[32 + i*4+3]))));
            acc[48 + i*4+0] = fmaf(ef0.z, a.x, fmaf(ef1.z, b.x,
                              fmaf(ef2.z, c.x, fmaf(ef3.z, d.x, acc[48 + i*4+0]))));
            acc[48 + i*4+1] = fmaf(ef0.z, a.y, fmaf(ef1.z, b.y,
                              fmaf(ef2.z, c.y, fmaf(ef3.z, d.y, acc[48 + i*4+1]))));
            acc[48 + i*4+2] = fmaf(ef0.z, a.z, fmaf(ef1.z, b.z,
                              fmaf(ef2.z, c.z, fmaf(ef3.z, d.z, acc[48 + i*4+2]))));
            acc[48 + i*4+3] = fmaf(ef0.z, a.w, fmaf(ef1.z, b.w,
                              fmaf(ef2.z, c.w, fmaf(ef3.z, d.w, acc[48 + i*4+3]))));
            acc[64 + i*4+0] = fmaf(ef0.w, a.x, fmaf(ef1.w, b.x,
                              fmaf(ef2.w, c.x, fmaf(ef3.w, d.x, acc[64 + i*4+0]))));
            acc[64 + i*4+1] = fmaf(ef0.w, a.y, fmaf(ef1.w, b.y,
                              fmaf(ef2.w, c.y, fmaf(ef3.w, d.y, acc[64 + i*4+1]))));
            acc[64 + i*4+2] = fmaf(ef0.w, a.z, fmaf(ef1.w, b.z,
                              fmaf(ef2.w, c.z, fmaf(ef3.w, d.z, acc[64 + i*4+2]))));
            acc[64 + i*4+3] = fmaf(ef0.w, a.w, fmaf(ef1.w, b.w,
                              fmaf(ef2.w, c.w, fmaf(ef3.w, d.w, acc[64 + i*4+3]))));
        }
    }
    for (; j < deg; ++j) {
        float4 ef = pp[2*j];
        float4 sp = pp[2*j+1];
        int src = __float_as_int(sp.x);
        const float4* vr = (const float4*)(v + (size_t)src * 16);
        #pragma unroll
        for (int i = 0; i < 4; ++i) {
            float4 a = vr[i];
            acc[     i*4+0] += a.x;
            acc[     i*4+1] += a.y;
            acc[     i*4+2] += a.z;
            acc[     i*4+3] += a.w;
            acc[16 + i*4+0] = fmaf(ef.x, a.x, acc[16 + i*4+0]);
            acc[16 + i*4+1] = fmaf(ef.x, a.y, acc[16 + i*4+1]);
            acc[16 + i*4+2] = fmaf(ef.x, a.z, acc[16 + i*4+2]);
            acc[16 + i*4+3] = fmaf(ef.x, a.w, acc[16 + i*4+3]);
            acc[32 + i*4+0] = fmaf(ef.y, a.x, acc[32 + i*4+0]);
            acc[32 + i*4+1] = fmaf(ef.y, a.y, acc[32 + i*4+1]);
            acc[32 + i*4+2] = fmaf(ef.y, a.z, acc[32 + i*4+2]);
            acc[32 + i*4+3] = fmaf(ef.y, a.w, acc[32 + i*4+3]);
            acc[48 + i*4+0] = fmaf(ef.z, a.x, acc[48 + i*4+0]);
            acc[48 + i*4+1] = fmaf(ef.z, a.y, acc[48 + i*4+1]);
            acc[48 + i*4+2] = fmaf(ef.z, a.z, acc[48 + i*4+2]);
            acc[48 + i*4+3] = fmaf(ef.z, a.w, acc[48 + i*4+3]);
            acc[64 + i*4+0] = fmaf(ef.w, a.x, acc[64 + i*4+0]);
            acc[64 + i*4+1] = fmaf(ef.w, a.y, acc[64 + i*4+1]);
            acc[64 + i*4+2] = fmaf(ef.w, a.z, acc[64 + i*4+2]);
            acc[64 + i*4+3] = fmaf(ef.w, a.w, acc[64 + i*4+3]);
        }
    }

    float val[16];
    if (active) {
        float vn[16];
        #pragma unroll
        for (int i = 0; i < 4; ++i) {
            float4 tv = *(const float4*)(v + (size_t)n * 16 + i * 4);
            vn[4*i+0] = tv.x; vn[4*i+1] = tv.y;
            vn[4*i+2] = tv.z; vn[4*i+3] = tv.w;
        }
        float scale = 1.0f / fmaxf((float)deg, 1.0f);
        #pragma unroll
        for (int o = 0; o < 16; ++o) {
            float a = 0.0f;
            #pragma unroll
            for (int i = 0; i < 16; ++i) {
                a = fmaf(acc[i], enet_b[i * 16 + o], a);           // S0 * B
                #pragma unroll
                for (int k = 0; k < 4; ++k)
                    a = fmaf(acc[16 + k * 16 + i],
                             enet_w[(i * 16 + o) * 4 + k], a);     // Sk * Wk
            }
            a = fmaf(a, scale, bias[o]);
            #pragma unroll
            for (int i = 0; i < 16; ++i)
                a = fmaf(vn[i], root[i * 16 + o], a);
            val[o] = a;
        }
        #pragma unroll
        for (int i = 0; i < 4; ++i)
            *(float4*)(out + (size_t)n * 16 + i * 4) =
                make_float4(val[4*i+0], val[4*i+1], val[4*i+2], val[4*i+3]);
    } else {
        #pragma unroll
        for (int o = 0; o < 16; ++o) val[o] = 0.0f;
    }

    // wave butterfly + LDS reduction of sum / sumsq per column
    float ssum[16], ssq[16];
    #pragma unroll
    for (int o = 0; o < 16; ++o) {
        float a = val[o];
        float b = a * a;
        #pragma unroll
        for (int m = 1; m < 64; m <<= 1) {
            a += __shfl_xor(a, m, 64);
            b += __shfl_xor(b, m, 64);
        }
        ssum[o] = a; ssq[o] = b;
    }
    __shared__ float part[4][32];
    int wave = threadIdx.x >> 6;
    int lane = threadIdx.x & 63;
    if (lane == 0) {
        #pragma unroll
        for (int o = 0; o < 16; ++o) {
            part[wave][o]      = ssum[o];
            part[wave][16 + o] = ssq[o];
        }
    }
    __syncthreads();
    if (threadIdx.x < 32) {
        float t = part[0][threadIdx.x] + part[1][threadIdx.x] +
                  part[2][threadIdx.x] + part[3][threadIdx.x];
        unsafeAtomicAdd(stats + threadIdx.x, t);
    }
}

// Kernel 6: BatchNorm (batch stats) + LeakyReLU, in place, float4-vectorized.
__global__ __launch_bounds__(256) void final_kernel(
    float* __restrict__ out,
    const float* __restrict__ stats,
    const float* __restrict__ gamma,
    const float* __restrict__ beta)
{
    int idx = blockIdx.x * 256 + threadIdx.x;      // float4 index
    if (idx >= N_NODES * 4) return;
    int o0 = (idx & 3) << 2;
    const float invN = 1.0f / (float)N_NODES;
    float4 x = *((const float4*)out + idx);
    float xs[4] = {x.x, x.y, x.z, x.w};
    float r[4];
    #pragma unroll
    for (int u = 0; u < 4; ++u) {
        int o = o0 + u;
        float mu = stats[o] * invN;
        float var = fmaxf(stats[16 + o] * invN - mu * mu, 0.0f);
        float y = fmaf(gamma[o] * (xs[u] - mu), rsqrtf(var + EPS), beta[o]);
        r[u] = (y >= 0.0f) ? y : SLOPE * y;
    }
    *((float4*)out + idx) = make_float4(r[0], r[1], r[2], r[3]);
}

extern "C" void kernel_launch(void* const* d_in, const int* in_sizes, int n_in,
                              void* d_out, int out_size, void* d_ws, size_t ws_size,
                              hipStream_t stream)
{
    const float* v = (const float*)d_in[0];
    const float* e = (const float*)d_in[1];
    const int* edge_index = (const int*)d_in[2];
    const float* enet_w = (const float*)d_in[3];
    const float* enet_b = (const float*)d_in[4];
    const float* root = (const float*)d_in[5];
    const float* bias = (const float*)d_in[6];
    const float* gamma = (const float*)d_in[7];
    const float* beta = (const float*)d_in[8];
    float* out = (float*)d_out;

    char* ws = (char*)d_ws;
    float4* P        = (float4*)ws;                 ws += (size_t)N_EDGES * 32;
    int*    hist     = (int*)ws;                    ws += (size_t)N_NODES * 4;
    int*    cursor   = (int*)ws;                    ws += (size_t)N_NODES * 4;
    float*  stats    = (float*)ws;                  ws += 32 * 4;
    int*    row_part = (int*)ws;                    ws += (size_t)N_NODES * 4;
    int*    bsum     = (int*)ws;                    ws += 512 * 4;
    int*    bsum_ex  = (int*)ws;

    // zero hist + cursor + stats (contiguous)
    hipMemsetAsync(hist, 0, (size_t)N_NODES * 4 * 2 + 32 * 4, stream);

    count_kernel<<<(N_EDGES / 4 + 255) / 256, 256, 0, stream>>>(edge_index, hist);
    scan1_kernel<<<NBLK, 256, 0, stream>>>(hist, row_part, bsum);
    scan2_kernel<<<1, 512, 0, stream>>>(bsum, bsum_ex);
    scatter_kernel<<<(N_EDGES + 255) / 256, 256, 0, stream>>>(
        e, edge_index, row_part, bsum_ex, cursor, P);
    gather_node_kernel<<<NBLK, 256, 0, stream>>>(
        v, P, hist, row_part, bsum_ex, enet_w, enet_b, root, bias, out, stats);
    final_kernel<<<(N_NODES * 4 + 255) / 256, 256, 0, stream>>>(
        out, stats, gamma, beta);
}